// Round 6
// baseline (611.187 us; speedup 1.0000x reference)
//
#include <hip/hip_runtime.h>
#include <hip/hip_bf16.h>
#include <stdint.h>

// x [4,2048,2048] fp32, W [8192,2048] fp32, gamma [2048] fp32 -> out [4,2048,8192] fp32
// C[M,N] = rmsnorm(x)[M,K] . Wq[N,K]^T * scale
#define M_ROWS 8192
#define K_DIM  2048
#define N_DIM  8192
#define W_ELEMS (N_DIM * K_DIM)
#define X_ELEMS (M_ROWS * K_DIM)
#define NT 32          // K_DIM / 64
#define ABSUM_BLOCKS 256

typedef __bf16 v8bf __attribute__((ext_vector_type(8)));
typedef float  v4f  __attribute__((ext_vector_type(4)));

__device__ inline unsigned short f2bf(float f) {
  uint32_t u = __builtin_bit_cast(uint32_t, f);
  uint32_t r = (u + 0x7fffu + ((u >> 16) & 1u)) >> 16;
  return (unsigned short)r;
}

__device__ inline void async_copy16(const void* g, void* l) {
  __builtin_amdgcn_global_load_lds(
      (const __attribute__((address_space(1))) void*)g,
      (__attribute__((address_space(3))) void*)l, 16, 0, 0);
}

// Per-wave redundant reduce of 256 partial doubles -> scale (no LDS, no barrier).
__device__ inline float scale_from_partials(const double* __restrict__ partials) {
  const int lane = threadIdx.x & 63;
  double d = partials[lane] + partials[lane + 64] +
             partials[lane + 128] + partials[lane + 192];
  for (int off = 32; off > 0; off >>= 1) d += __shfl_down(d, off);
  d = __shfl(d, 0);
  return (float)fmax(d * (1.0 / (double)W_ELEMS), 1e-5);
}

// ---------------- Kernel 1: fused prep ----------------
// blocks [0, ABSUM_BLOCKS): per-block partial sum(|W|) -> partials[pb]
//   (partials live in the head of d_out: written here, read by quant, then
//   overwritten by gemm — stream-ordered, no races, no extra ws space).
// blocks [ABSUM_BLOCKS, ...): rmsnorm row -> bf16, fully-coalesced split-row.
__global__ __launch_bounds__(256) void prep_kernel(const float* __restrict__ X,
                                                   const float* __restrict__ gamma,
                                                   const float* __restrict__ W,
                                                   unsigned short* __restrict__ Xn,
                                                   double* __restrict__ partials) {
  __shared__ double wsumd[4];
  __shared__ float wsumf[4];
  const int t = threadIdx.x;
  const int lane = t & 63, wid = t >> 6;

  if (blockIdx.x < ABSUM_BLOCKS) {
    const int pb = blockIdx.x;
    int tid = pb * 256 + t;
    const float4* W4 = (const float4*)W;
    const int n4 = W_ELEMS / 4;
    double acc = 0.0;
    for (int i = tid; i < n4; i += ABSUM_BLOCKS * 256) {
      float4 v = W4[i];
      acc += (double)fabsf(v.x) + (double)fabsf(v.y) +
             (double)fabsf(v.z) + (double)fabsf(v.w);
    }
    for (int off = 32; off > 0; off >>= 1) acc += __shfl_down(acc, off);
    if (lane == 0) wsumd[wid] = acc;
    __syncthreads();
    if (t == 0) partials[pb] = wsumd[0] + wsumd[1] + wsumd[2] + wsumd[3];
    return;
  }

  const int row = blockIdx.x - ABSUM_BLOCKS;
  const float4* xr = (const float4*)(X + (size_t)row * K_DIM);
  float4 a = xr[t];          // elems 4t..4t+3
  float4 b = xr[t + 256];    // elems 1024+4t..1024+4t+3
  float ss = a.x * a.x + a.y * a.y + a.z * a.z + a.w * a.w +
             b.x * b.x + b.y * b.y + b.z * b.z + b.w * b.w;
  for (int off = 32; off > 0; off >>= 1) ss += __shfl_down(ss, off);
  if (lane == 0) wsumf[wid] = ss;
  __syncthreads();
  float total = wsumf[0] + wsumf[1] + wsumf[2] + wsumf[3];
  float inv = 1.0f / sqrtf(total * (1.0f / (float)K_DIM) + 1e-6f);
  const float4* gr = (const float4*)gamma;
  float4 g0 = gr[t];
  float4 g1 = gr[t + 256];
  union { unsigned short h[4]; uint2 u; } pa, pb;
  pa.h[0] = f2bf((a.x * inv) * g0.x);
  pa.h[1] = f2bf((a.y * inv) * g0.y);
  pa.h[2] = f2bf((a.z * inv) * g0.z);
  pa.h[3] = f2bf((a.w * inv) * g0.w);
  pb.h[0] = f2bf((b.x * inv) * g1.x);
  pb.h[1] = f2bf((b.y * inv) * g1.y);
  pb.h[2] = f2bf((b.z * inv) * g1.z);
  pb.h[3] = f2bf((b.w * inv) * g1.w);
  uint2* orow = (uint2*)(Xn + (size_t)row * K_DIM);
  orow[t] = pa.u;
  orow[t + 256] = pb.u;
}

// ---------------- Kernel 2: ternary quantize W -> bf16 {-1,0,1} ----------------
// Scale computed inline from partials (reduce_kernel removed: it was a 1-block
// full-device serialization + extra launch). Block 0 publishes scale[0] for gemm.
__global__ __launch_bounds__(256) void quant_kernel(const float* __restrict__ W,
                                                    const double* __restrict__ partials,
                                                    float* __restrict__ scale_out,
                                                    unsigned short* __restrict__ Wq) {
  const float s = scale_from_partials(partials);
  const int t = threadIdx.x;
  if (blockIdx.x == 0 && t == 0) scale_out[0] = s;
  const float4* W4 = (const float4*)W + (size_t)blockIdx.x * 512;
  float4 a = W4[t];
  float4 b = W4[t + 256];
  union { unsigned short h[4]; uint2 u; } pa, pb;
  pa.h[0] = f2bf(rintf(fminf(1.f, fmaxf(-1.f, a.x / s))));
  pa.h[1] = f2bf(rintf(fminf(1.f, fmaxf(-1.f, a.y / s))));
  pa.h[2] = f2bf(rintf(fminf(1.f, fmaxf(-1.f, a.z / s))));
  pa.h[3] = f2bf(rintf(fminf(1.f, fmaxf(-1.f, a.w / s))));
  pb.h[0] = f2bf(rintf(fminf(1.f, fmaxf(-1.f, b.x / s))));
  pb.h[1] = f2bf(rintf(fminf(1.f, fmaxf(-1.f, b.y / s))));
  pb.h[2] = f2bf(rintf(fminf(1.f, fmaxf(-1.f, b.z / s))));
  pb.h[3] = f2bf(rintf(fminf(1.f, fmaxf(-1.f, b.w / s))));
  uint2* o = (uint2*)(Wq + (size_t)blockIdx.x * 2048);
  o[t] = pa.u;
  o[t + 256] = pb.u;
}

// ---------------- Kernel 3: 256x256 tile, BK=64, 8-wave, minimal-barrier ----------------
// REVERTED vs r5: r3's 4x4 supertile XCD mapping + plain float4 C stores (r5's
// remap/nt-stores raised FETCH 202->303, WRITE 285->352 — both regressions).
// NEW vs r3: barriers cut 8 -> 2 per K-tile. Dependency audit: the only true
// sync points are p1-end and p3-end. A wave's ds_reads are consumed (lgkm) by
// its own MFMAs before it reaches the next barrier, so:
//  RAW (stage->read): Ah1[t] staged t-1 p0, gated by p1-end VM8+bar (read p2);
//    Ah0/Bh1/Bh0[t+1] staged t-1 p2/p2/p3, gated by p3-end VM8+bar (read at
//    p3-preload / t+1 p0 / t+1 p1). vmcnt ledger IDENTICAL to the r3-validated
//    one (same stage order, same VM8 positions, 8 loads in flight).
//  WAR (read->stage): p2 stages overwrite regions read at p0/p1 (gated by
//    p1-end bar); p0 stage overwrites region read at t-1 p2 (gated by t-1
//    p3-end bar); p3 stage overwrites b0f-preload region (gated by p1-end bar).
// Each sync point is VM8 -> s_barrier -> ""-asm memory fence -> sched_barrier(0)
// so no LDS read can be hoisted above the barrier (rule-18 class hazard).
__global__ __launch_bounds__(512, 2) void gemm_kernel(
    const unsigned short* __restrict__ A,   // x_norm bf16 [M,K]
    const unsigned short* __restrict__ B,   // wq bf16 [N,K]
    const float* __restrict__ scale,
    float* __restrict__ C) {
  __shared__ __align__(16) char lds[131072];

  const int tid = threadIdx.x;
  const int lane = tid & 63;
  const int wave = tid >> 6;
  const int wm = wave & 1;    // M half: wave owns 128 rows
  const int wn = wave >> 1;   // N quarter: wave owns 64 cols

  // r3 mapping: XCD-aware swizzle + 4x4 supertile (best measured: FETCH 202 MB)
  const int bid = blockIdx.x;
  const int swz = (bid & 7) * 128 + (bid >> 3);
  const int st = swz >> 4, wi = swz & 15;
  const int mb = (st >> 3) * 4 + (wi >> 2);
  const int nb = (st & 7) * 4 + (wi & 3);
  const int m0 = mb * 256;
  const int n0 = nb * 256;

  const int srow3 = lane >> 3;
  const int scg = (lane & 7) ^ srow3;

  const int aoff_a = wm * 8192 + (lane & 15) * 128;
  const int boff_b = wn * 4096 + (lane & 15) * 128;
  const int swzk0 = ((lane >> 4) ^ (lane & 7)) << 4;
  const int swzk1 = ((4 + (lane >> 4)) ^ (lane & 7)) << 4;

  v4f acc[8][4] = {};
  v8bf af[4][2];
  v8bf b0f[2][2];
  v8bf b1f[2][2];

#define STAGE_A(B_, H_, KT_) do {                                              \
    _Pragma("unroll")                                                          \
    for (int j = 0; j < 2; ++j) {                                              \
      const int chunk_ = wave * 2 + j;                                         \
      const int slot_ = chunk_ * 8 + srow3;                                    \
      const int row_ = ((slot_ >> 6) << 7) + ((H_) << 6) + (slot_ & 63);       \
      async_copy16(A + (size_t)(m0 + row_) * K_DIM + ((KT_) << 6) + (scg << 3),\
                   lds + (B_) * 32768 + (H_) * 16384 + chunk_ * 1024);         \
    } } while (0)

#define STAGE_B(B_, H_, KT_) do {                                              \
    _Pragma("unroll")                                                          \
    for (int j = 0; j < 2; ++j) {                                              \
      const int chunk_ = wave * 2 + j;                                         \
      const int slot_ = chunk_ * 8 + srow3;                                    \
      const int row_ = ((slot_ >> 5) << 6) + ((H_) << 5) + (slot_ & 31);       \
      async_copy16(B + (size_t)(n0 + row_) * K_DIM + ((KT_) << 6) + (scg << 3),\
                   lds + 65536 + (B_) * 32768 + (H_) * 16384 + chunk_ * 1024); \
    } } while (0)

#define LOADA(B_, QM_) do {                                                    \
    _Pragma("unroll")                                                          \
    for (int tm = 0; tm < 4; ++tm) {                                           \
      af[tm][0] = *(const v8bf*)(lds + (B_) * 32768 + (QM_) * 16384 +          \
                                 aoff_a + tm * 2048 + swzk0);                  \
      af[tm][1] = *(const v8bf*)(lds + (B_) * 32768 + (QM_) * 16384 +          \
                                 aoff_a + tm * 2048 + swzk1);                  \
    } } while (0)

#define LOADB(B_, QN_, DST) do {                                               \
    _Pragma("unroll")                                                          \
    for (int tn = 0; tn < 2; ++tn) {                                           \
      DST[tn][0] = *(const v8bf*)(lds + 65536 + (B_) * 32768 + (QN_) * 16384 + \
                                  boff_b + tn * 2048 + swzk0);                 \
      DST[tn][1] = *(const v8bf*)(lds + 65536 + (B_) * 32768 + (QN_) * 16384 + \
                                  boff_b + tn * 2048 + swzk1);                 \
    } } while (0)

#define MMAC(BF, QM_, QN_) do {                                                \
    _Pragma("unroll")                                                          \
    for (int ks = 0; ks < 2; ++ks)                                             \
    _Pragma("unroll")                                                          \
    for (int tm = 0; tm < 4; ++tm)                                             \
    _Pragma("unroll")                                                          \
    for (int tn = 0; tn < 2; ++tn)                                             \
      acc[(QM_) * 4 + tm][(QN_) * 2 + tn] =                                    \
          __builtin_amdgcn_mfma_f32_16x16x32_bf16(                             \
              BF[tn][ks], af[tm][ks],                                          \
              acc[(QM_) * 4 + tm][(QN_) * 2 + tn], 0, 0, 0);                   \
  } while (0)

// Sync point: all-waves load-retire gate + compiler fences (no LDS-op hoisting).
#define SYNC8() do {                                                           \
    asm volatile("s_waitcnt vmcnt(8)" ::: "memory");                           \
    __builtin_amdgcn_s_barrier();                                              \
    asm volatile("" ::: "memory");                                             \
    __builtin_amdgcn_sched_barrier(0);                                         \
  } while (0)

#define TILE(T_, B_) do {                                                      \
    const int t1_ = ((T_) + 1 < NT) ? (T_) + 1 : NT - 1;                       \
    const int t2_ = ((T_) + 2 < NT) ? (T_) + 2 : NT - 1;                       \
    /* p0: (qm0,qn0) — b0f preloaded last tile */                              \
    LOADA(B_, 0);                                                              \
    STAGE_A(1 - (B_), 1, t1_);                                                 \
    __builtin_amdgcn_s_setprio(1); MMAC(b0f, 0, 0);                            \
    __builtin_amdgcn_s_setprio(0);                                             \
    /* p1: (qm0,qn1) */                                                        \
    LOADB(B_, 1, b1f);                                                         \
    __builtin_amdgcn_s_setprio(1); MMAC(b1f, 0, 1);                            \
    __builtin_amdgcn_s_setprio(0);                                             \
    SYNC8();                                                                   \
    /* p2: (qm1,qn0) */                                                        \
    LOADA(B_, 1);                                                              \
    STAGE_A(B_, 0, t2_);                                                       \
    STAGE_B(B_, 1, t2_);                                                       \
    __builtin_amdgcn_s_setprio(1); MMAC(b0f, 1, 0);                            \
    __builtin_amdgcn_s_setprio(0);                                             \
    /* p3: (qm1,qn1) */                                                        \
    STAGE_B(B_, 0, t2_);                                                       \
    __builtin_amdgcn_s_setprio(1); MMAC(b1f, 1, 1);                            \
    __builtin_amdgcn_s_setprio(0);                                             \
    SYNC8();                                                                   \
    LOADB(1 - (B_), 0, b0f);                                                   \
  } while (0)

  // Prologue: stage order matches steady-state ledger (identical to r3).
  STAGE_A(0, 0, 0);   // Ah0[0]
  STAGE_B(0, 0, 0);   // Bh0[0]
  STAGE_B(0, 1, 0);   // Bh1[0]
  STAGE_A(0, 1, 0);   // Ah1[0]   (plays t-1 p0)
  STAGE_A(1, 0, 1);   // Ah0[1]   (t-1 p2)
  STAGE_B(1, 1, 1);   // Bh1[1]   (t-1 p2)
  STAGE_B(1, 0, 1);   // Bh0[1]   (t-1 p3)
  SYNC8();            // 14 -> 8: Ah0[0]/Bh0[0]/Bh1[0] landed, all waves
  LOADB(0, 0, b0f);   // preload b0f for tile 0

  for (int t = 0; t < NT; t += 2) {
    TILE(t, 0);
    TILE(t + 1, 1);
  }

  // Epilogue (verified layout: per acc[tm][tn], M = lane&15, N = (lane>>4)*4+reg)
  const float s = scale[0];
  const int mBase = m0 + wm * 128 + (lane & 15);
  const int nBase = n0 + wn * 64 + ((lane >> 4) << 2);
#pragma unroll
  for (int tm = 0; tm < 8; ++tm) {
#pragma unroll
    for (int tn = 0; tn < 4; ++tn) {
      float4 v;
      v.x = acc[tm][tn][0] * s;
      v.y = acc[tm][tn][1] * s;
      v.z = acc[tm][tn][2] * s;
      v.w = acc[tm][tn][3] * s;
      *(float4*)&C[(size_t)(mBase + tm * 16) * N_DIM + (nBase + tn * 16)] = v;
    }
  }

#undef STAGE_A
#undef STAGE_B
#undef LOADA
#undef LOADB
#undef MMAC
#undef SYNC8
#undef TILE
}

extern "C" void kernel_launch(void* const* d_in, const int* in_sizes, int n_in,
                              void* d_out, int out_size, void* d_ws, size_t ws_size,
                              hipStream_t stream) {
  const float* x = (const float*)d_in[0];
  const float* w = (const float*)d_in[1];
  const float* gamma = (const float*)d_in[2];
  float* out = (float*)d_out;

  // ws layout: [0,16): float scale; [16, 16+32MB): xn bf16; then wq bf16 (32MB).
  // partials (256 doubles) live at the head of d_out: prep writes, quant reads,
  // gemm overwrites — stream-ordered, zero extra workspace.
  float* scale_f = (float*)d_ws;
  unsigned short* xn = (unsigned short*)((char*)d_ws + 16);
  unsigned short* wq = (unsigned short*)((char*)d_ws + 16 + (size_t)X_ELEMS * 2);
  double* partials = (double*)out;

  prep_kernel<<<ABSUM_BLOCKS + M_ROWS, 256, 0, stream>>>(x, gamma, w, xn, partials);
  quant_kernel<<<W_ELEMS / 2048, 256, 0, stream>>>(w, partials, scale_f, wq);
  gemm_kernel<<<(M_ROWS / 256) * (N_DIM / 256), 512, 0, stream>>>(xn, wq, scale_f, out);
}

// Round 9
// 598.923 us; speedup vs baseline: 1.0205x; 1.0205x over previous
//
#include <hip/hip_runtime.h>
#include <hip/hip_bf16.h>
#include <stdint.h>

// x [4,2048,2048] fp32, W [8192,2048] fp32, gamma [2048] fp32 -> out [4,2048,8192] fp32
// C[M,N] = rmsnorm(x)[M,K] . Wq[N,K]^T * scale
#define M_ROWS 8192
#define K_DIM  2048
#define N_DIM  8192
#define W_ELEMS (N_DIM * K_DIM)
#define X_ELEMS (M_ROWS * K_DIM)
#define NT 32          // K_DIM / 64
#define ABSUM_BLOCKS 256

typedef __bf16 v8bf __attribute__((ext_vector_type(8)));
typedef float  v4f  __attribute__((ext_vector_type(4)));

__device__ inline unsigned short f2bf(float f) {
  uint32_t u = __builtin_bit_cast(uint32_t, f);
  uint32_t r = (u + 0x7fffu + ((u >> 16) & 1u)) >> 16;
  return (unsigned short)r;
}

__device__ inline void async_copy16(const void* g, void* l) {
  __builtin_amdgcn_global_load_lds(
      (const __attribute__((address_space(1))) void*)g,
      (__attribute__((address_space(3))) void*)l, 16, 0, 0);
}

// Per-wave redundant reduce of 256 partial doubles -> scale (no LDS, no barrier).
__device__ inline float scale_from_partials(const double* __restrict__ partials) {
  const int lane = threadIdx.x & 63;
  double d = partials[lane] + partials[lane + 64] +
             partials[lane + 128] + partials[lane + 192];
  for (int off = 32; off > 0; off >>= 1) d += __shfl_down(d, off);
  d = __shfl(d, 0);
  return (float)fmax(d * (1.0 / (double)W_ELEMS), 1e-5);
}

// ---------------- Kernel 1: fused prep (unchanged from r6, passing) ----------------
__global__ __launch_bounds__(256) void prep_kernel(const float* __restrict__ X,
                                                   const float* __restrict__ gamma,
                                                   const float* __restrict__ W,
                                                   unsigned short* __restrict__ Xn,
                                                   double* __restrict__ partials) {
  __shared__ double wsumd[4];
  __shared__ float wsumf[4];
  const int t = threadIdx.x;
  const int lane = t & 63, wid = t >> 6;

  if (blockIdx.x < ABSUM_BLOCKS) {
    const int pb = blockIdx.x;
    int tid = pb * 256 + t;
    const float4* W4 = (const float4*)W;
    const int n4 = W_ELEMS / 4;
    double acc = 0.0;
    for (int i = tid; i < n4; i += ABSUM_BLOCKS * 256) {
      float4 v = W4[i];
      acc += (double)fabsf(v.x) + (double)fabsf(v.y) +
             (double)fabsf(v.z) + (double)fabsf(v.w);
    }
    for (int off = 32; off > 0; off >>= 1) acc += __shfl_down(acc, off);
    if (lane == 0) wsumd[wid] = acc;
    __syncthreads();
    if (t == 0) partials[pb] = wsumd[0] + wsumd[1] + wsumd[2] + wsumd[3];
    return;
  }

  const int row = blockIdx.x - ABSUM_BLOCKS;
  const float4* xr = (const float4*)(X + (size_t)row * K_DIM);
  float4 a = xr[t];
  float4 b = xr[t + 256];
  float ss = a.x * a.x + a.y * a.y + a.z * a.z + a.w * a.w +
             b.x * b.x + b.y * b.y + b.z * b.z + b.w * b.w;
  for (int off = 32; off > 0; off >>= 1) ss += __shfl_down(ss, off);
  if (lane == 0) wsumf[wid] = ss;
  __syncthreads();
  float total = wsumf[0] + wsumf[1] + wsumf[2] + wsumf[3];
  float inv = 1.0f / sqrtf(total * (1.0f / (float)K_DIM) + 1e-6f);
  const float4* gr = (const float4*)gamma;
  float4 g0 = gr[t];
  float4 g1 = gr[t + 256];
  union { unsigned short h[4]; uint2 u; } pa, pb;
  pa.h[0] = f2bf((a.x * inv) * g0.x);
  pa.h[1] = f2bf((a.y * inv) * g0.y);
  pa.h[2] = f2bf((a.z * inv) * g0.z);
  pa.h[3] = f2bf((a.w * inv) * g0.w);
  pb.h[0] = f2bf((b.x * inv) * g1.x);
  pb.h[1] = f2bf((b.y * inv) * g1.y);
  pb.h[2] = f2bf((b.z * inv) * g1.z);
  pb.h[3] = f2bf((b.w * inv) * g1.w);
  uint2* orow = (uint2*)(Xn + (size_t)row * K_DIM);
  orow[t] = pa.u;
  orow[t + 256] = pb.u;
}

// ---------------- Kernel 2: ternary quantize W -> bf16 {-1,0,1} (unchanged) ----------------
__global__ __launch_bounds__(256) void quant_kernel(const float* __restrict__ W,
                                                    const double* __restrict__ partials,
                                                    float* __restrict__ scale_out,
                                                    unsigned short* __restrict__ Wq) {
  const float s = scale_from_partials(partials);
  const int t = threadIdx.x;
  if (blockIdx.x == 0 && t == 0) scale_out[0] = s;
  const float4* W4 = (const float4*)W + (size_t)blockIdx.x * 512;
  float4 a = W4[t];
  float4 b = W4[t + 256];
  union { unsigned short h[4]; uint2 u; } pa, pb;
  pa.h[0] = f2bf(rintf(fminf(1.f, fmaxf(-1.f, a.x / s))));
  pa.h[1] = f2bf(rintf(fminf(1.f, fmaxf(-1.f, a.y / s))));
  pa.h[2] = f2bf(rintf(fminf(1.f, fmaxf(-1.f, a.z / s))));
  pa.h[3] = f2bf(rintf(fminf(1.f, fmaxf(-1.f, a.w / s))));
  pb.h[0] = f2bf(rintf(fminf(1.f, fmaxf(-1.f, b.x / s))));
  pb.h[1] = f2bf(rintf(fminf(1.f, fmaxf(-1.f, b.y / s))));
  pb.h[2] = f2bf(rintf(fminf(1.f, fmaxf(-1.f, b.z / s))));
  pb.h[3] = f2bf(rintf(fminf(1.f, fmaxf(-1.f, b.w / s))));
  uint2* o = (uint2*)(Wq + (size_t)blockIdx.x * 2048);
  o[t] = pa.u;
  o[t + 256] = pb.u;
}

// ---------------- Kernel 3: 256x256, BK=64, 8-wave, uniform per-phase template ----------------
// Same schedule as the r7 submission (stage ledger, barrier count, vmcnt values
// identical). De-risked: explicit lgkmcnt(0) asm removed — ds_reads are plain
// C++ LDS loads, so the compiler inserts precise per-dependency lgkmcnt before
// each MFMA consumer (finer than a blanket wait; m97-verified behavior). One
// sched_barrier(0) per phase (after the closing barrier) pins post-barrier
// ds_reads below the barrier.
//
// Per phase: {ds_reads; 1 half-tile stage (2 gload_lds); barrier; setprio(1);
// 16 MFMA; setprio(0); vmcnt(6); barrier; sched_barrier}.
// Stages: p0 Ah0[t+1]->buf^1, p1 Bh1[t+1]->buf^1, p2 Ah1[t+1]->buf^1,
//         p3 Bh0[t+2]->buf.  FIFO lag exactly 4 phases; each vmcnt(6)
// (outstanding 8 -> 6) retires precisely the half staged 4 phases earlier
// (>1200 cy runway), and the following all-waves barrier publishes it before
// the next phase's ds_reads (no per-wave-vmcnt race — r2 lesson).
// Reads: p0 LOADA(h0) 8; p1 LOADB(h1) 4; p2 LOADA(h1) 8; p3 b0f-preload 4.
// WAR: every stage target's last ds_read completed >=7 barriers earlier.
// Tail clamps re-stage only dead regions. No conditional barriers; all waits
// satisfiable by construction (no hang mode).
__global__ __launch_bounds__(512, 2) void gemm_kernel(
    const unsigned short* __restrict__ A,   // x_norm bf16 [M,K]
    const unsigned short* __restrict__ B,   // wq bf16 [N,K]
    const float* __restrict__ scale,
    float* __restrict__ C) {
  __shared__ __align__(16) char lds[131072];

  const int tid = threadIdx.x;
  const int lane = tid & 63;
  const int wave = tid >> 6;
  const int wm = wave & 1;    // M half: wave owns 128 rows
  const int wn = wave >> 1;   // N quarter: wave owns 64 cols

  // r3 mapping: XCD-aware swizzle + 4x4 supertile (best measured: FETCH 202 MB)
  const int bid = blockIdx.x;
  const int swz = (bid & 7) * 128 + (bid >> 3);
  const int st = swz >> 4, wi = swz & 15;
  const int mb = (st >> 3) * 4 + (wi >> 2);
  const int nb = (st & 7) * 4 + (wi & 3);
  const int m0 = mb * 256;
  const int n0 = nb * 256;

  const int srow3 = lane >> 3;
  const int scg = (lane & 7) ^ srow3;

  const int aoff_a = wm * 8192 + (lane & 15) * 128;
  const int boff_b = wn * 4096 + (lane & 15) * 128;
  const int swzk0 = ((lane >> 4) ^ (lane & 7)) << 4;
  const int swzk1 = ((4 + (lane >> 4)) ^ (lane & 7)) << 4;

  v4f acc[8][4] = {};
  v8bf af[4][2];
  v8bf b0f[2][2];
  v8bf b1f[2][2];

#define STAGE_A(B_, H_, KT_) do {                                              \
    _Pragma("unroll")                                                          \
    for (int j = 0; j < 2; ++j) {                                              \
      const int chunk_ = wave * 2 + j;                                         \
      const int slot_ = chunk_ * 8 + srow3;                                    \
      const int row_ = ((slot_ >> 6) << 7) + ((H_) << 6) + (slot_ & 63);       \
      async_copy16(A + (size_t)(m0 + row_) * K_DIM + ((KT_) << 6) + (scg << 3),\
                   lds + (B_) * 32768 + (H_) * 16384 + chunk_ * 1024);         \
    } } while (0)

#define STAGE_B(B_, H_, KT_) do {                                              \
    _Pragma("unroll")                                                          \
    for (int j = 0; j < 2; ++j) {                                              \
      const int chunk_ = wave * 2 + j;                                         \
      const int slot_ = chunk_ * 8 + srow3;                                    \
      const int row_ = ((slot_ >> 5) << 6) + ((H_) << 5) + (slot_ & 31);       \
      async_copy16(B + (size_t)(n0 + row_) * K_DIM + ((KT_) << 6) + (scg << 3),\
                   lds + 65536 + (B_) * 32768 + (H_) * 16384 + chunk_ * 1024); \
    } } while (0)

#define LOADA(B_, QM_) do {                                                    \
    _Pragma("unroll")                                                          \
    for (int tm = 0; tm < 4; ++tm) {                                           \
      af[tm][0] = *(const v8bf*)(lds + (B_) * 32768 + (QM_) * 16384 +          \
                                 aoff_a + tm * 2048 + swzk0);                  \
      af[tm][1] = *(const v8bf*)(lds + (B_) * 32768 + (QM_) * 16384 +          \
                                 aoff_a + tm * 2048 + swzk1);                  \
    } } while (0)

#define LOADB(B_, QN_, DST) do {                                               \
    _Pragma("unroll")                                                          \
    for (int tn = 0; tn < 2; ++tn) {                                           \
      DST[tn][0] = *(const v8bf*)(lds + 65536 + (B_) * 32768 + (QN_) * 16384 + \
                                  boff_b + tn * 2048 + swzk0);                 \
      DST[tn][1] = *(const v8bf*)(lds + 65536 + (B_) * 32768 + (QN_) * 16384 + \
                                  boff_b + tn * 2048 + swzk1);                 \
    } } while (0)

#define MMAC(BF, QM_, QN_) do {                                                \
    _Pragma("unroll")                                                          \
    for (int ks = 0; ks < 2; ++ks)                                             \
    _Pragma("unroll")                                                          \
    for (int tm = 0; tm < 4; ++tm)                                             \
    _Pragma("unroll")                                                          \
    for (int tn = 0; tn < 2; ++tn)                                             \
      acc[(QM_) * 4 + tm][(QN_) * 2 + tn] =                                    \
          __builtin_amdgcn_mfma_f32_16x16x32_bf16(                             \
              BF[tn][ks], af[tm][ks],                                          \
              acc[(QM_) * 4 + tm][(QN_) * 2 + tn], 0, 0, 0);                   \
  } while (0)

#define BAR()    __builtin_amdgcn_s_barrier()
#define SCHED0() __builtin_amdgcn_sched_barrier(0)
#define VMG6()   asm volatile("s_waitcnt vmcnt(6)" ::: "memory")

#define PHASE(READS_, STAGE_, MM_) do {                                        \
    READS_;                                                                    \
    STAGE_;                                                                    \
    BAR();                                                                     \
    __builtin_amdgcn_s_setprio(1); MM_;                                        \
    __builtin_amdgcn_s_setprio(0);                                             \
    VMG6(); BAR(); SCHED0();                                                   \
  } while (0)

#define TILE(T_, B_) do {                                                      \
    const int t1_ = ((T_) + 1 < NT) ? (T_) + 1 : NT - 1;                       \
    const int t2_ = ((T_) + 2 < NT) ? (T_) + 2 : NT - 1;                       \
    PHASE(LOADA(B_, 0),            STAGE_A(1 - (B_), 0, t1_), MMAC(b0f, 0, 0));\
    PHASE(LOADB(B_, 1, b1f),       STAGE_B(1 - (B_), 1, t1_), MMAC(b1f, 0, 1));\
    PHASE(LOADA(B_, 1),            STAGE_A(1 - (B_), 1, t1_), MMAC(b0f, 1, 0));\
    PHASE(LOADB(1 - (B_), 0, b0f), STAGE_B(B_, 0, t2_),       MMAC(b1f, 1, 1));\
  } while (0)

  // Prologue in steady-state FIFO order (emulates tiles t=-2/-1):
  STAGE_B(0, 0, 0);   // Bh0[0] -> buf0   (t-2 p3)
  STAGE_A(0, 0, 0);   // Ah0[0] -> buf0   (t-1 p0)
  STAGE_B(0, 1, 0);   // Bh1[0] -> buf0   (t-1 p1)
  STAGE_A(0, 1, 0);   // Ah1[0] -> buf0   (t-1 p2)
  STAGE_B(1, 0, 1);   // Bh0[1] -> buf1   (t-1 p3)
  VMG6();             // 10 -> 6: Bh0[0], Ah0[0] landed (this wave)
  BAR(); SCHED0();    // ...and all waves'
  LOADB(0, 0, b0f);   // preload b0f for tile 0 (buf0.Bh0)

  for (int t = 0; t < NT; t += 2) {
    TILE(t, 0);
    TILE(t + 1, 1);
  }

  // Epilogue (verified layout: per acc[tm][tn], M = lane&15, N = (lane>>4)*4+reg)
  const float s = scale[0];
  const int mBase = m0 + wm * 128 + (lane & 15);
  const int nBase = n0 + wn * 64 + ((lane >> 4) << 2);
#pragma unroll
  for (int tm = 0; tm < 8; ++tm) {
#pragma unroll
    for (int tn = 0; tn < 4; ++tn) {
      float4 v;
      v.x = acc[tm][tn][0] * s;
      v.y = acc[tm][tn][1] * s;
      v.z = acc[tm][tn][2] * s;
      v.w = acc[tm][tn][3] * s;
      *(float4*)&C[(size_t)(mBase + tm * 16) * N_DIM + (nBase + tn * 16)] = v;
    }
  }

#undef STAGE_A
#undef STAGE_B
#undef LOADA
#undef LOADB
#undef MMAC
#undef BAR
#undef SCHED0
#undef VMG6
#undef PHASE
#undef TILE
}

extern "C" void kernel_launch(void* const* d_in, const int* in_sizes, int n_in,
                              void* d_out, int out_size, void* d_ws, size_t ws_size,
                              hipStream_t stream) {
  const float* x = (const float*)d_in[0];
  const float* w = (const float*)d_in[1];
  const float* gamma = (const float*)d_in[2];
  float* out = (float*)d_out;

  // ws layout: [0,16): float scale; [16, 16+32MB): xn bf16; then wq bf16 (32MB).
  // partials (256 doubles) live at the head of d_out: prep writes, quant reads,
  // gemm overwrites — stream-ordered, zero extra workspace.
  float* scale_f = (float*)d_ws;
  unsigned short* xn = (unsigned short*)((char*)d_ws + 16);
  unsigned short* wq = (unsigned short*)((char*)d_ws + 16 + (size_t)X_ELEMS * 2);
  double* partials = (double*)out;

  prep_kernel<<<ABSUM_BLOCKS + M_ROWS, 256, 0, stream>>>(x, gamma, w, xn, partials);
  quant_kernel<<<W_ELEMS / 2048, 256, 0, stream>>>(w, partials, scale_f, wq);
  gemm_kernel<<<(M_ROWS / 256) * (N_DIM / 256), 512, 0, stream>>>(xn, wq, scale_f, out);
}